// Round 1
// baseline (51805.969 us; speedup 1.0000x reference)
//
#include <hip/hip_runtime.h>
#include <math.h>

// Problem constants
#define B_   64
#define S_   512
#define D_   256
#define H_   512
#define G4   2048           // 4H
#define K0   768            // D + H   (layer 0)
#define K1   1024           // H + H   (layer 1)
#define NWG  256
#define NAH  128            // WGs assigned to layer 0 (group A); rest layer 1 (group B)
#define NTHR 256
#define UPW  4              // hidden units per WG
#define NCOL 16             // 4 gates * UPW columns per WG
#define CK   64             // K-chunk staged through LDS

// ws layout (float indices). cnt/epoch on separate cachelines.
#define OFF_CNT 0
#define OFF_EPO 32
#define OFF_SCL 64
#define OFF_H0  512
#define OFF_H1  (OFF_H0 + 2*B_*H_)
#define OFF_C0  (OFF_H1 + 2*B_*H_)
#define OFF_C1  (OFF_C0 + B_*H_)
#define OFF_END (OFF_C1 + B_*H_)

__device__ __forceinline__ float sigm(float v) { return 1.0f / (1.0f + expf(-v)); }

// Zero all persistent state + precompute exp(efw). Runs (stream-ordered) before
// the persistent kernel on every call -> deterministic across graph replays.
__global__ void lstm_init(const float* __restrict__ efw, float* __restrict__ ws) {
  int stride = gridDim.x * blockDim.x;
  for (int j = blockIdx.x * blockDim.x + threadIdx.x; j < OFF_END; j += stride) {
    float v = 0.0f;
    if (j >= OFF_SCL && j < OFF_SCL + D_) v = expf(efw[j - OFF_SCL]);
    ws[j] = v;
  }
}

// Persistent cooperative kernel. 256 WGs x 256 threads; ~86KB LDS forces
// 1 WG/CU so all 256 WGs are co-resident (grid == CU count).
// Group A (wg<128): layer 0 at time t=r.   Group B: layer 1 at time t=r-1.
// One epoch-counter grid barrier per round; h buffers double-buffered by
// round parity; c-state is WG-exclusive (no races).
__launch_bounds__(NTHR, 1)
__global__ void lstm_persist(const float* __restrict__ x,
                             const float* __restrict__ W0,
                             const float* __restrict__ b0,
                             const float* __restrict__ W1,
                             const float* __restrict__ b1,
                             float* __restrict__ out,
                             float* __restrict__ ws)
{
  __shared__ float wW[K1][NCOL];        // 64 KB  weight slice [k][col], col = gate*4+uu
  __shared__ float aT[CK][B_ + 1];      // 16.6KB A-chunk, k-major, +1 pad -> 2-way banks
  __shared__ float zB[4][B_][UPW + 1];  // 5.1 KB gate exchange, +1 pad
  __shared__ float scl[D_];             // 1 KB   exp(efw)

  const int  wg  = blockIdx.x;
  const int  tid = threadIdx.x;
  const bool isA = (wg < NAH);
  const int  u0  = (isA ? wg : wg - NAH) * UPW;
  const int  K   = isA ? K0 : K1;
  const int  nch = K / CK;              // 12 (A) / 16 (B)

  float* h0 = ws + OFF_H0;              // [2][B_][H_]
  float* h1 = ws + OFF_H1;
  float* cs = ws + (isA ? OFF_C0 : OFF_C1);   // [B_][H_], WG-exclusive units
  unsigned* cnt = (unsigned*)ws + OFF_CNT;
  unsigned* epo = (unsigned*)ws + OFF_EPO;

  // Stage this WG's weight slice into LDS (once). col cl = g*4+uu -> global col g*512+u0+uu.
  {
    const float* W = isA ? W0 : W1;
    for (int i = tid; i < K * NCOL; i += NTHR) {
      int k = i >> 4, cl = i & 15;
      int g = cl >> 2, uu = cl & 3;
      wW[k][cl] = W[(size_t)k * G4 + g * H_ + u0 + uu];
    }
  }
  for (int i = tid; i < D_; i += NTHR) scl[i] = ws[OFF_SCL + i];

  const int bb = tid & 63;              // batch row for GEMM phase
  const int cg = tid >> 6;              // gate index (cols cg*4 .. cg*4+3)
  float bias[4];
  {
    const float* bv = isA ? b0 : b1;
#pragma unroll
    for (int j = 0; j < 4; ++j) bias[j] = bv[cg * H_ + u0 + j];
  }
  const int b2 = tid & 63;              // batch row for update phase
  const int uu = tid >> 6;              // unit sub-index for update phase

  for (int r = 0; r <= S_; ++r) {
    const int  p   = r & 1;
    const bool act = isA ? (r < S_) : (r >= 1);
    if (act) {
      const int t = isA ? r : r - 1;
      const float* hp0 = h0 + (size_t)(p ^ 1) * B_ * H_;
      const float* hp1 = h1 + (size_t)(p ^ 1) * B_ * H_;
      float a0 = 0.f, a1 = 0.f, a2 = 0.f, a3 = 0.f;

      for (int c = 0; c < nch; ++c) {
        __syncthreads();                // protect aT reuse
        // Stage chunk: 64 k x 64 rows, transposed into aT[k][row].
#pragma unroll
        for (int i = 0; i < 4; ++i) {
          int idx = tid + NTHR * i;     // 0..1023
          int row = idx >> 4;           // 0..63
          int kk  = (idx & 15) << 2;    // 0,4,..,60
          int gk  = c * CK + kk;
          float4 v;
          if (isA) {
            if (gk < D_) {              // x part, scaled by exp(efw)
              v = *(const float4*)(x + (size_t)(row * S_ + t) * D_ + gk);
              float4 sc = *(const float4*)(&scl[gk]);
              v.x *= sc.x; v.y *= sc.y; v.z *= sc.z; v.w *= sc.w;
            } else {                    // h0_prev part
              v = *(const float4*)(hp0 + (size_t)row * H_ + (gk - D_));
            }
          } else {
            if (gk < H_) v = *(const float4*)(hp0 + (size_t)row * H_ + gk);        // h0[t]
            else         v = *(const float4*)(hp1 + (size_t)row * H_ + (gk - H_)); // h1[t-1]
          }
          aT[kk + 0][row] = v.x; aT[kk + 1][row] = v.y;
          aT[kk + 2][row] = v.z; aT[kk + 3][row] = v.w;
        }
        __syncthreads();
        // Accumulate: thread (bb, cg) -> 4 gate columns of gate cg, row bb.
        const float* wrow = &wW[c * CK][0];
#pragma unroll
        for (int kk = 0; kk < CK; ++kk) {
          float  a = aT[kk][bb];                                  // 2-way banks (free)
          float4 w = *(const float4*)(wrow + kk * NCOL + cg * 4); // wave-uniform broadcast
          a0 += a * w.x; a1 += a * w.y; a2 += a * w.z; a3 += a * w.w;
        }
      }

      // Exchange gates: thread (bb,cg) holds gate cg for units u0+0..3.
      zB[cg][bb][0] = a0 + bias[0];
      zB[cg][bb][1] = a1 + bias[1];
      zB[cg][bb][2] = a2 + bias[2];
      zB[cg][bb][3] = a3 + bias[3];
      __syncthreads();

      // Pointwise cell update: thread (b2, uu) owns (row b2, unit u0+uu).
      {
        float zi = zB[0][b2][uu], zf = zB[1][b2][uu];
        float zg = zB[2][b2][uu], zo = zB[3][b2][uu];
        int   ui = u0 + uu;
        float c_ = cs[b2 * H_ + ui];
        float i_ = sigm(zi);
        float f_ = sigm(zf + c_) * 0.9f;   // decayed forget gate (DECAY=0.1)
        float g_ = tanhf(zg);
        float o_ = sigm(zo);
        float cn = f_ * c_ + i_ * g_;
        float hn = o_ * tanhf(cn);
        cs[b2 * H_ + ui] = cn;
        float* hw = (isA ? h0 : h1) + (size_t)p * B_ * H_ + b2 * H_ + ui;
        *hw = hn;
        if (!isA) out[((size_t)b2 * S_ + t) * H_ + ui] = hn;
      }
    }

    // ---- grid barrier (epoch counter, agent scope) ----
    __syncthreads();                    // drains each wave's vmcnt -> stores in L2
    if (tid == 0) {
      __threadfence();                  // agent-scope release (L2 writeback)
      unsigned v = __hip_atomic_fetch_add(cnt, 1u, __ATOMIC_RELAXED,
                                          __HIP_MEMORY_SCOPE_AGENT);
      if (v == (unsigned)(r + 1) * NWG - 1u)
        __hip_atomic_store(epo, (unsigned)(r + 1), __ATOMIC_RELEASE,
                           __HIP_MEMORY_SCOPE_AGENT);
    }
    const unsigned tgt = (unsigned)(r + 1);
    while (__hip_atomic_load(epo, __ATOMIC_ACQUIRE, __HIP_MEMORY_SCOPE_AGENT) < tgt)
      __builtin_amdgcn_s_sleep(8);
  }
}

extern "C" void kernel_launch(void* const* d_in, const int* in_sizes, int n_in,
                              void* d_out, int out_size, void* d_ws, size_t ws_size,
                              hipStream_t stream) {
  const float* x   = (const float*)d_in[0];
  const float* W0  = (const float*)d_in[1];
  const float* b0  = (const float*)d_in[2];
  const float* W1  = (const float*)d_in[3];
  const float* b1  = (const float*)d_in[4];
  const float* efw = (const float*)d_in[5];
  float* out = (float*)d_out;
  float* ws  = (float*)d_ws;

  if (ws_size < (size_t)OFF_END * sizeof(float)) return;  // need ~0.8 MB scratch

  lstm_init<<<256, 256, 0, stream>>>(efw, ws);
  lstm_persist<<<NWG, NTHR, 0, stream>>>(x, W0, b0, W1, b1, out, ws);
}